// Round 5
// baseline (240.988 us; speedup 1.0000x reference)
//
#include <hip/hip_runtime.h>

// FlashAttention fwd, causal, no scale. B=2,H=16,S=2048,D=128, fp32 in/out.
// R5: 32 rows/wave (2 m-tiles) -> kf/vf LDS reads amortize over 2x MFMA
// (LDS read volume 2.3 GB -> 1.2 GB, was the 70%-busy pipe in R4);
// xor3 = (row^(row>>3))&7 swizzle kills the c/c+8 bank-quad collision
// (R4: 5.37M conflict cycles); Q pre-scaled by log2e -> exp2f softmax.
// WG = 128 threads (2 waves), BM=64, BN=64, LDS 40KB -> 4 WG/CU.
// History: R2 scratch demotion (runtime-bound mt loop); R3 244us latency-
// bound serial softmax; R4 93us S^T-orientation, LDS-pipe-bound.

#define SQ 2048
#define DH 128
#define BM 64
#define BN 64
#define NELEM 8388608   // B*H*S*D
#define LOG2E 1.44269504088896340736f

typedef _Float16 f16x8 __attribute__((ext_vector_type(8)));
typedef float f32x4 __attribute__((ext_vector_type(4)));
typedef unsigned short u16x8 __attribute__((ext_vector_type(8)));

typedef __attribute__((address_space(3))) void lds_t;
typedef __attribute__((address_space(1))) void gmem_t;

__device__ __forceinline__ void gload16(void* lds, const void* g) {
  __builtin_amdgcn_global_load_lds((const gmem_t*)g, (lds_t*)lds, 16, 0, 0);
}
__device__ __forceinline__ unsigned short f2h(float f) {
  return __builtin_bit_cast(unsigned short, (_Float16)f);   // v_cvt_f16_f32 RNE
}
__device__ __forceinline__ int xor3(int row) { return (row ^ (row >> 3)) & 7; }

// ---------------- pre-kernel: K fp32->fp16 flat; V fp32 -> Vt[bh][d][s] fp16
__global__ __launch_bounds__(256) void prep(const float* __restrict__ k,
                                            const float* __restrict__ v,
                                            unsigned short* __restrict__ ko,
                                            unsigned short* __restrict__ vt) {
  const int tid = threadIdx.x;
  const int bx = blockIdx.x;
  if (bx < 2048) {
    // V transpose tile: 32 s x 128 d
    __shared__ unsigned short lv[32 * 132];   // pad 128->132
    const int bh = bx >> 6;
    const int s0 = (bx & 63) * 32;
    const float* vs = v + ((size_t)bh * SQ + s0) * DH;
    #pragma unroll
    for (int it = 0; it < 4; ++it) {
      int fi = it * 256 + tid;       // 1024 float4 units
      int sL = fi >> 5;              // 0..31
      int dL = (fi & 31) * 4;
      float4 val = *(const float4*)(vs + (size_t)sL * DH + dL);
      ushort4 o;
      o.x = f2h(val.x); o.y = f2h(val.y); o.z = f2h(val.z); o.w = f2h(val.w);
      *(ushort4*)(lv + sL * 132 + dL) = o;
    }
    __syncthreads();
    #pragma unroll
    for (int it = 0; it < 2; ++it) {
      int ci = it * 256 + tid;       // 512 chunks: dL = ci>>2, sg = ci&3
      int dL = ci >> 2;
      int sg = ci & 3;
      u16x8 o;
      #pragma unroll
      for (int j = 0; j < 8; ++j) o[j] = lv[(sg * 8 + j) * 132 + dL];
      *(u16x8*)(vt + ((size_t)bh * DH + dL) * SQ + s0 + sg * 8) = o;
    }
  } else {
    // K conversion: 2048 blocks grid-stride over NELEM/4 float4 chunks
    const int NT = NELEM / 4;
    for (int i = (bx - 2048) * 256 + tid; i < NT; i += 2048 * 256) {
      float4 val = ((const float4*)k)[i];
      ushort4 o;
      o.x = f2h(val.x); o.y = f2h(val.y); o.z = f2h(val.z); o.w = f2h(val.w);
      ((ushort4*)ko)[i] = o;
    }
  }
}

// ---------------- main flash-attention kernel ----------------
// Grid 1024, 128 threads (2 waves, 32 rows each as 2 m-tiles of 16).
// XCD-aware swizzle identical to R4 (per-CU kt sum = 66).
__global__ __launch_bounds__(128, 2) void fattn(const float* __restrict__ Qf,
                                                const unsigned short* __restrict__ Kh,
                                                const unsigned short* __restrict__ Vth,
                                                float* __restrict__ Out) {
  __shared__ char smem[40960];  // [0,16K) sK (Q staging aliases), [16K,32K) sV,
                                // [32K,40K) sP: 4KB/wave (32 rows x 128B)
  const int tid  = threadIdx.x;
  const int wave = tid >> 6;
  const int lane = tid & 63;
  const int quad = lane >> 4;
  const int c    = lane & 15;

  const int t     = (int)blockIdx.x;
  const int xcd   = t & 7;
  const int idx   = t >> 3;
  const int cu    = idx & 31;
  const int round = idx >> 5;               // 0..3
  const int bh    = xcd * 4 + round;
  int qb;
  {
    int b0 = (cu + 8 * (round >> 1)) & 31;
    qb = (round & 1) ? (31 - b0) : b0;      // rounds: q, 31-q, q+8, 31-(q+8)
  }
  const int rowbase = qb * BM;

  char* sK = smem;
  char* sV = smem + 16384;
  char* sP = smem + 32768 + wave * 4096;

  // tile-local row bases for this wave's two m-tiles
  const int rb0 = wave * 16;
  const int rb1 = 32 + wave * 16;

  // ---- stage Q (fp32 -> fp16 * LOG2E) into sK region, swizzled ----
  const float* Qg = Qf + ((size_t)bh * SQ + rowbase) * DH;
  #pragma unroll
  for (int it = 0; it < 16; ++it) {
    int gi  = it * 128 + tid;      // 2048 units of 4 floats
    int row = gi >> 5;             // 0..63
    int sub = gi & 31;
    float4 qv = *(const float4*)(Qg + (size_t)row * DH + sub * 4);
    ushort4 h;
    h.x = f2h(qv.x * LOG2E); h.y = f2h(qv.y * LOG2E);
    h.z = f2h(qv.z * LOG2E); h.w = f2h(qv.w * LOG2E);
    int gr = (sub >> 1) ^ xor3(row);
    *(ushort4*)(smem + row * 256 + gr * 16 + (sub & 1) * 8) = h;
  }
  __syncthreads();
  f16x8 qf[2][4];
  #pragma unroll
  for (int mt = 0; mt < 2; ++mt) {
    int row = (mt ? rb1 : rb0) + c;
    #pragma unroll
    for (int ch = 0; ch < 4; ++ch) {
      int gr = (ch * 4 + quad) ^ xor3(row);
      qf[mt][ch] = *(const f16x8*)(smem + row * 256 + gr * 16);
    }
  }
  __syncthreads();

  f32x4 acc[2][8];   // O^T: [mt][dt]; d = dt*16+quad*4+r, query row = c
  #pragma unroll
  for (int mt = 0; mt < 2; ++mt)
    #pragma unroll
    for (int dt = 0; dt < 8; ++dt) acc[mt][dt] = (f32x4){0.f, 0.f, 0.f, 0.f};
  float mo[2] = {-1e30f, -1e30f}, lrow[2] = {0.f, 0.f};

  const unsigned short* Kbase = Kh + (size_t)bh * SQ * DH;
  const unsigned short* Vbase = Vth + (size_t)bh * DH * SQ;
  const int nkt = qb + 1;

  for (int kt = 0; kt < nkt; ++kt) {
    const int k0 = kt * BN;
    // ---- stage K (64 keys x 128 d) and Vt (128 d x 64 keys) ----
    #pragma unroll
    for (int it = 0; it < 8; ++it) {
      int gi  = it * 128 + tid;
      int key = gi >> 4;
      int dg  = (gi & 15) ^ xor3(key);
      gload16(sK + (it * 128 + wave * 64) * 16,
              Kbase + (size_t)(k0 + key) * DH + dg * 8);
    }
    #pragma unroll
    for (int it = 0; it < 8; ++it) {
      int gi = it * 128 + tid;
      int d  = gi >> 3;
      int kg = (gi & 7) ^ xor3(d);
      gload16(sV + (it * 128 + wave * 64) * 16,
              Vbase + (size_t)d * SQ + k0 + kg * 8);
    }
    __syncthreads();

    const bool diag = (kt == qb);
    const int ntm0 = diag ? wave : 3;        // last key-16-block needed, mt0
    const int ntm1 = diag ? 2 + wave : 3;    // mt1

    // ---- S^T = K Q^T: sc[mt][nt][r] = S^T[key=nt*16+quad*4+r][row=c] ----
    f32x4 sc[2][4];
    #pragma unroll
    for (int mt = 0; mt < 2; ++mt)
      #pragma unroll
      for (int nt = 0; nt < 4; ++nt) sc[mt][nt] = (f32x4){0.f, 0.f, 0.f, 0.f};
    #pragma unroll
    for (int nt = 0; nt < 4; ++nt) {
      int keyl = nt * 16 + c;
      int xr = xor3(keyl);
      bool do0 = (nt <= ntm0);               // wave-uniform
      bool do1 = (nt <= ntm1);
      #pragma unroll
      for (int ch = 0; ch < 4; ++ch) {
        f16x8 kf = *(const f16x8*)(sK + keyl * 256 + (((ch * 4 + quad) ^ xr) * 16));
        if (do0) sc[0][nt] = __builtin_amdgcn_mfma_f32_16x16x32_f16(kf, qf[0][ch], sc[0][nt], 0, 0, 0);
        if (do1) sc[1][nt] = __builtin_amdgcn_mfma_f32_16x16x32_f16(kf, qf[1][ch], sc[1][nt], 0, 0, 0);
      }
    }

    // ---- causal mask (diag tile): skipped nt -> -inf; boundary nt masked ----
    if (diag) {
      #pragma unroll
      for (int mt = 0; mt < 2; ++mt) {
        int rl  = (mt ? rb1 : rb0) + c;      // tile-local row
        int ntm = mt ? ntm1 : ntm0;
        #pragma unroll
        for (int nt = 0; nt < 4; ++nt)
          #pragma unroll
          for (int r = 0; r < 4; ++r) {
            int key = nt * 16 + quad * 4 + r;
            if (nt > ntm || (nt == ntm && key > rl)) sc[mt][nt][r] = -1e30f;
          }
      }
    }

    // ---- online softmax (base-2; Q pre-scaled by log2e) ----
    #pragma unroll
    for (int mt = 0; mt < 2; ++mt) {
      float cm = -1e30f;
      #pragma unroll
      for (int nt = 0; nt < 4; ++nt)
        #pragma unroll
        for (int r = 0; r < 4; ++r) cm = fmaxf(cm, sc[mt][nt][r]);
      cm = fmaxf(cm, __shfl_xor(cm, 16));
      cm = fmaxf(cm, __shfl_xor(cm, 32));
      float mn = fmaxf(mo[mt], cm);
      float al = exp2f(mo[mt] - mn);
      float rs = 0.f;
      ushort4 pk[4];
      #pragma unroll
      for (int nt = 0; nt < 4; ++nt)
        #pragma unroll
        for (int r = 0; r < 4; ++r) {
          float p = exp2f(sc[mt][nt][r] - mn);
          rs += p;
          ((unsigned short*)&pk[nt])[r] = f2h(p);
        }
      rs += __shfl_xor(rs, 16);
      rs += __shfl_xor(rs, 32);
      lrow[mt] = lrow[mt] * al + rs;
      mo[mt] = mn;
      #pragma unroll
      for (int dt = 0; dt < 8; ++dt) acc[mt][dt] *= al;
      // P write: region row rp = mt*16 + c, 64 keys, swizzled b64
      int rp = mt * 16 + c;
      int xr = xor3(rp);
      #pragma unroll
      for (int nt = 0; nt < 4; ++nt) {
        int g8 = nt * 2 + (quad >> 1);
        *(ushort4*)(sP + rp * 128 + ((g8 ^ xr) * 16) + (quad & 1) * 8) = pk[nt];
      }
    }

    // ---- O^T += Vt * P (vf reused across both m-tiles) ----
    const bool pv0full = !diag;              // mt0 needs only ch0 on diag
    #pragma unroll
    for (int ch = 0; ch < 2; ++ch) {
      bool d0 = (ch == 0) | pv0full;
      f16x8 pf0, pf1;
      {
        int rp = c;  int xr = xor3(rp);
        if (d0) pf0 = *(const f16x8*)(sP + rp * 128 + (((ch * 4 + quad) ^ xr) * 16));
      }
      {
        int rp = 16 + c;  int xr = xor3(rp);
        pf1 = *(const f16x8*)(sP + rp * 128 + (((ch * 4 + quad) ^ xr) * 16));
      }
      #pragma unroll
      for (int dt = 0; dt < 8; ++dt) {
        int d = dt * 16 + c;
        f16x8 vf = *(const f16x8*)(sV + d * 128 + (((ch * 4 + quad) ^ xor3(d)) * 16));
        if (d0) acc[0][dt] = __builtin_amdgcn_mfma_f32_16x16x32_f16(vf, pf0, acc[0][dt], 0, 0, 0);
        acc[1][dt] = __builtin_amdgcn_mfma_f32_16x16x32_f16(vf, pf1, acc[1][dt], 0, 0, 0);
      }
    }
    __syncthreads();   // protect sK/sV/sP before next staging
  }

  // ---- epilogue: O[row][d] = acc / l ----
  #pragma unroll
  for (int mt = 0; mt < 2; ++mt) {
    const float inv = 1.0f / lrow[mt];
    const int rowg = rowbase + (mt ? rb1 : rb0) + c;
    float* op = Out + ((size_t)bh * SQ + rowg) * DH;
    #pragma unroll
    for (int dt = 0; dt < 8; ++dt) {
      float4 o;
      o.x = acc[mt][dt][0] * inv;
      o.y = acc[mt][dt][1] * inv;
      o.z = acc[mt][dt][2] * inv;
      o.w = acc[mt][dt][3] * inv;
      *(float4*)(op + dt * 16 + quad * 4) = o;
    }
  }
}

extern "C" void kernel_launch(void* const* d_in, const int* in_sizes, int n_in,
                              void* d_out, int out_size, void* d_ws, size_t ws_size,
                              hipStream_t stream) {
  const float* q = (const float*)d_in[0];
  const float* k = (const float*)d_in[1];
  const float* v = (const float*)d_in[2];
  // d_in[3] (mask) is guaranteed tril-causal; handled analytically.
  float* out = (float*)d_out;

  unsigned short* kws = (unsigned short*)d_ws;           // 16 MiB
  unsigned short* vws = kws + NELEM;                     // 16 MiB (transposed)

  prep<<<4096, 256, 0, stream>>>(k, v, kws, vws);
  fattn<<<1024, 128, 0, stream>>>(q, kws, vws, out);
}